// Round 18
// baseline (479.326 us; speedup 1.0000x reference)
//
#include <hip/hip_runtime.h>

// Activations: BATCH-MAJOR [b][vertex][channel], fp16.
// k_pdw: FUSED pool+dwconv gather. dwconv(pool(x)) = 27-tap gather with
// precomputed composed tables cidx[v][27], cval[v][27] (k_prep_idx; fixed per
// level). Single-batch XCD-pinned blocks -> per-XCD INPUT slice <=1.6MB (L2-
// resident); pool math in packed fp16 (v_pk_fma_f16); no LDS; no MFMA
// coupling (round 13 law). Eliminates k_pool + the bufB round-trip (~90MB).
// k_gemm: persistent async-LDS A + MFMA. NSLICE=2 (CO=256) computes two col
// slices SEQUENTIALLY ("#pragma unroll 1" is load-bearing: round 16 showed
// unrolling co-allocates both slices' accs -> VGPR 204 -> occ 7.5%).
// k_gemm_head: lvl4 conv + fused head MFMA -> z directly (no bufA store).
// d_ws layout:
//   bufA @ 0 (25,690,112)
//   cidx @ 25,690,112 (2,540,160 ints) | cval @ 28,230,272 (2,540,160 f32)
//   bufC @ 77,070,336 (51,380,224) | pwT @ 128,450,560 (688,128)
//   bheadT @ 129,138,688 (16,384) | dwT @ 129,155,072 (32,256)
//   z @ 129,187,328 (21,676,032) | xs @ 150,863,360 (524,288)
// NOTE: never raise __launch_bounds__ min-waves on MFMA kernels (round 5).

typedef _Float16 half8 __attribute__((ext_vector_type(8)));
typedef _Float16 h2    __attribute__((ext_vector_type(2)));
typedef float    f32x4 __attribute__((ext_vector_type(4)));

__device__ __forceinline__ float4 ld4(const float* p) { return *(const float4*)p; }

__device__ __forceinline__ float lo16f(unsigned u) {
  _Float16 h; unsigned short s = (unsigned short)(u & 0xffffu);
  __builtin_memcpy(&h, &s, 2); return (float)h;
}
__device__ __forceinline__ float hi16f(unsigned u) {
  _Float16 h; unsigned short s = (unsigned short)(u >> 16);
  __builtin_memcpy(&h, &s, 2); return (float)h;
}
__device__ __forceinline__ float h2f(unsigned short s) {
  _Float16 h; __builtin_memcpy(&h, &s, 2); return (float)h;
}
__device__ __forceinline__ unsigned short hbits(float v) {
  _Float16 h = (_Float16)v; unsigned short u; __builtin_memcpy(&u, &h, 2); return u;
}
__device__ __forceinline__ unsigned pk2h(float a, float b) {
  return (unsigned)hbits(a) | ((unsigned)hbits(b) << 16);
}
__device__ __forceinline__ h2 uash2(unsigned u) { h2 r; __builtin_memcpy(&r, &u, 4); return r; }
__device__ __forceinline__ unsigned h2asu(h2 h) { unsigned u; __builtin_memcpy(&u, &h, 4); return u; }
// split v = hi + lo*2^-11, lo pre-scaled by 2048
__device__ __forceinline__ void split2h(float v, unsigned short& h, unsigned short& l) {
  _Float16 hf = (_Float16)v;
  float hif = (float)hf;
  _Float16 lf = (_Float16)((v - hif) * 2048.0f);
  __builtin_memcpy(&h, &hf, 2); __builtin_memcpy(&l, &lf, 2);
}
// async 16B global -> LDS (no VGPR writeback)
__device__ __forceinline__ void gload_lds16(const unsigned short* g, unsigned short* l) {
  __builtin_amdgcn_global_load_lds(
      (const __attribute__((address_space(1))) unsigned int*)g,
      (__attribute__((address_space(3))) unsigned int*)l, 16, 0, 0);
}

// ---------------- merged prep: pw split tables + head W + dwT transpose ----------------
__global__ __launch_bounds__(256) void k_prep_all(
    const float* __restrict__ pw0, const float* __restrict__ pw1,
    const float* __restrict__ pw2, const float* __restrict__ pw3,
    const float* __restrict__ dwh, const float* __restrict__ pwh,
    const float* __restrict__ dw0, const float* __restrict__ dw1,
    const float* __restrict__ dw2, const float* __restrict__ dw3,
    unsigned short* __restrict__ dstPw, unsigned short* __restrict__ dstHead,
    float* __restrict__ dstDw)
{
  const int blk = blockIdx.x, t = threadIdx.x;
  if (blk < 672) {
    const int b = blk;
    const float* src; int ci_sh, co, f, off;
    if (b < 256)      { src = pw0; ci_sh = 8; co = 256; f = b*256 + t;       off = 0; }
    else if (b < 512) { src = pw1; ci_sh = 8; co = 256; f = (b-256)*256 + t; off = 65536; }
    else if (b < 640) { src = pw2; ci_sh = 8; co = 128; f = (b-512)*256 + t; off = 131072; }
    else              { src = pw3; ci_sh = 7; co = 64;  f = (b-640)*256 + t; off = 163840; }
    const int n = f >> ci_sh, k = f & ((1 << ci_sh) - 1);
    float v = src[(size_t)k*co + n];
    unsigned short h, l; split2h(v, h, l);
    dstPw[off + f]          = h;
    dstPw[172032 + off + f] = l;
  } else if (blk < 680) {
    const int i = (blk - 672)*256 + t;   // 2048 = 32*64
    const int n = i >> 6, c = i & 63;
    float v = 0.f;
    if (n < 27) v = dwh[c*9 + n/3] * pwh[c*3 + n%3];
    unsigned short h, l; split2h(v, h, l);
    dstHead[i] = h; dstHead[2048 + i] = l;
  } else {
    const int i = (blk - 680)*256 + t;
    if (i >= 8064) return;
    const float* src; int rel, C, off;
    if (i < 2304)      { src = dw0; rel = i;        C = 256; off = 0; }
    else if (i < 4608) { src = dw1; rel = i - 2304; C = 256; off = 2304; }
    else if (i < 6912) { src = dw2; rel = i - 4608; C = 256; off = 4608; }
    else               { src = dw3; rel = i - 6912; C = 128; off = 6912; }
    const int s = rel / C, c = rel % C;
    dstDw[off + rel] = src[c*9 + s];
  }
}

// ---------------- k_prep_idx: composed pool+spiral tables per level ----------------
// cidx[v][27] = col[3*sp[v,s]+k], cval[v][27] = val[3*sp[v,s]+k].
// Element offsets: lvl1 0 (1568v), lvl2 42336 (3136v), lvl3 127008 (6272v),
// lvl4 296352 (12544v); total 635040.
__global__ __launch_bounds__(256) void k_prep_idx(
    const int* __restrict__ sp3, const int* __restrict__ col3, const float* __restrict__ val3,
    const int* __restrict__ sp2, const int* __restrict__ col2, const float* __restrict__ val2,
    const int* __restrict__ sp1, const int* __restrict__ col1, const float* __restrict__ val1,
    const int* __restrict__ sp0, const int* __restrict__ col0, const float* __restrict__ val0,
    int* __restrict__ cidx, float* __restrict__ cval)
{
  const int e = blockIdx.x*256 + threadIdx.x;
  if (e >= 635040) return;
  const int* sp; const int* col; const float* val; int rel, off;
  if (e < 42336)       { sp = sp3; col = col3; val = val3; rel = e;          off = 0; }
  else if (e < 127008) { sp = sp2; col = col2; val = val2; rel = e - 42336;  off = 42336; }
  else if (e < 296352) { sp = sp1; col = col1; val = val1; rel = e - 127008; off = 127008; }
  else                 { sp = sp0; col = col0; val = val0; rel = e - 296352; off = 296352; }
  const int v = rel / 27, j = rel - v*27;
  const int s = j / 3, k = j - s*3;
  const int u = sp[v*9 + s];
  cidx[off + rel] = col[3*u + k];
  cval[off + rel] = val[3*u + k];
}

// ---------------- k_samp: grid-sample only -> xs[b][p][c] fp16 (16 blocks) ----------------
__global__ __launch_bounds__(256) void k_samp(
    const float* __restrict__ uv, const float* __restrict__ feat,
    unsigned short* __restrict__ xs)
{
  __shared__ float feat_l[256][17];
  const int tid = threadIdx.x;
  const int b   = blockIdx.x;

  const float* fr = feat + ((size_t)b*256 + tid)*16;
  #pragma unroll
  for (int i = 0; i < 16; i += 4) {
    float4 f = ld4(fr + i);
    feat_l[tid][i+0] = f.x; feat_l[tid][i+1] = f.y;
    feat_l[tid][i+2] = f.z; feat_l[tid][i+3] = f.w;
  }
  #pragma unroll 4
  for (int p = 0; p < 64; ++p) {
    float gx = uv[((size_t)b*64 + p)*2 + 0];
    float gy = uv[((size_t)b*64 + p)*2 + 1];
    gx = fminf(fmaxf((gx - 0.5f)*2.f, -1.f), 1.f);
    gy = fminf(fmaxf((gy - 0.5f)*2.f, -1.f), 1.f);
    float x = (gx + 1.f)*0.5f*3.f;
    float y = (gy + 1.f)*0.5f*3.f;
    float fx = floorf(x), fy = floorf(y);
    int ix0 = (int)fx, iy0 = (int)fy;
    float wx = x - fx, wy = y - fy;
    int ix1 = ix0 + 1 > 3 ? 3 : ix0 + 1;
    int iy1 = iy0 + 1 > 3 ? 3 : iy0 + 1;
    float v00 = feat_l[tid][iy0*4+ix0];
    float v01 = feat_l[tid][iy0*4+ix1];
    float v10 = feat_l[tid][iy1*4+ix0];
    float v11 = feat_l[tid][iy1*4+ix1];
    float xv = (1.f-wy)*((1.f-wx)*v00 + wx*v01) + wy*((1.f-wx)*v10 + wx*v11);
    xs[((size_t)b*64 + p)*256 + tid] = hbits(xv);
  }
}

// ---------------- k_up: x0[b][v][c] = sum_p up[v][p]*xs[b][p][c], 16 verts/block ----------------
__global__ __launch_bounds__(256) void k_up(
    const unsigned short* __restrict__ xs, const float* __restrict__ up,
    unsigned short* __restrict__ x0)
{
  const int tid = threadIdx.x;
  const int b   = blockIdx.y;
  const int v0  = blockIdx.x * 16;

  float acc[16];
  #pragma unroll
  for (int i = 0; i < 16; ++i) acc[i] = 0.f;

  #pragma unroll 8
  for (int p = 0; p < 64; ++p) {
    const float xv = h2f(xs[((size_t)b*64 + p)*256 + tid]);
    #pragma unroll
    for (int i = 0; i < 16; ++i)
      acc[i] += up[(size_t)(v0+i)*64 + p] * xv;   // wave-uniform -> scalar
  }
  #pragma unroll
  for (int i = 0; i < 16; ++i)
    x0[((size_t)b*784 + v0 + i)*256 + tid] = hbits(acc[i]);
}

// ---------------- k_pdw: fused pool+dwconv 27-tap gather -> m-major panel ----------------
// SINGLE-BATCH blocks: XCD = blockIdx%8, phase-major. 2 vertices/thread.
// Pool combine in packed fp16 (inputs are fp16 exact; <=1 extra ulp vs
// round-17's fp32-then-round pool); dw accumulate in fp32.
template<int CI>
__global__ __launch_bounds__(256) void k_pdw(
    const unsigned short* __restrict__ pin, const int* __restrict__ cidx,
    const float* __restrict__ cval, const float* __restrict__ dwT,
    unsigned short* __restrict__ aout, int Vin, int VG)
{
  constexpr int KG    = CI/8;
  constexpr int SLOTS = 256/KG;
  constexpr int VPB   = 2*SLOTS;

  const int t     = threadIdx.x;
  const int xcd   = blockIdx.x & 7;
  const int i     = blockIdx.x >> 3;
  const int phase = (i >= VG) ? 1 : 0;
  const int vg    = i - phase*VG;
  const int b     = xcd + 8*phase;
  const int kg    = t & (KG - 1);
  const int slot  = t / KG;
  const int va    = vg*VPB + slot;
  const int vb2   = va + SLOTS;

  const unsigned short* base = pin + (size_t)b*Vin*CI + 8*kg;
  float y0[8], y1[8];
  #pragma unroll
  for (int j = 0; j < 8; ++j) { y0[j] = 0.f; y1[j] = 0.f; }

  #pragma unroll
  for (int s = 0; s < 9; ++s) {
    const float4 wa = *(const float4*)(dwT + s*CI + 8*kg);
    const float4 wb = *(const float4*)(dwT + s*CI + 8*kg + 4);
    #pragma unroll
    for (int hv = 0; hv < 2; ++hv) {
      const int vv = hv ? vb2 : va;
      float* y = hv ? y1 : y0;
      const int o27 = vv*27 + s*3;
      const int i0 = cidx[o27], i1 = cidx[o27+1], i2 = cidx[o27+2];
      const _Float16 c0 = (_Float16)cval[o27], c1 = (_Float16)cval[o27+1], c2 = (_Float16)cval[o27+2];
      const h2 w0 = {c0, c0}, w1 = {c1, c1}, w2 = {c2, c2};
      const uint4 g0 = *(const uint4*)(base + (size_t)i0*CI);
      const uint4 g1 = *(const uint4*)(base + (size_t)i1*CI);
      const uint4 g2 = *(const uint4*)(base + (size_t)i2*CI);
      unsigned p0 = h2asu(uash2(g0.x)*w0 + uash2(g1.x)*w1 + uash2(g2.x)*w2);
      unsigned p1 = h2asu(uash2(g0.y)*w0 + uash2(g1.y)*w1 + uash2(g2.y)*w2);
      unsigned p2 = h2asu(uash2(g0.z)*w0 + uash2(g1.z)*w1 + uash2(g2.z)*w2);
      unsigned p3 = h2asu(uash2(g0.w)*w0 + uash2(g1.w)*w1 + uash2(g2.w)*w2);
      y[0] += wa.x*lo16f(p0); y[1] += wa.y*hi16f(p0);
      y[2] += wa.z*lo16f(p1); y[3] += wa.w*hi16f(p1);
      y[4] += wb.x*lo16f(p2); y[5] += wb.y*hi16f(p2);
      y[6] += wb.z*lo16f(p3); y[7] += wb.w*hi16f(p3);
    }
  }
  uint4 q0, q1;
  q0.x = pk2h(y0[0], y0[1]); q0.y = pk2h(y0[2], y0[3]);
  q0.z = pk2h(y0[4], y0[5]); q0.w = pk2h(y0[6], y0[7]);
  q1.x = pk2h(y1[0], y1[1]); q1.y = pk2h(y1[2], y1[3]);
  q1.z = pk2h(y1[4], y1[5]); q1.w = pk2h(y1[6], y1[7]);
  *(uint4*)(aout + (size_t)(va *16 + b)*CI + 8*kg) = q0;
  *(uint4*)(aout + (size_t)(vb2*16 + b)*CI + 8*kg) = q1;
}

// ---------------- k_gemm: persistent async-LDS A + MFMA ----------------
template<int CI, int COT, int NTW, int NSLICE, bool RELU>
__global__ __launch_bounds__(256) void k_gemm(
    const unsigned short* __restrict__ A,
    const unsigned short* __restrict__ bhp, const unsigned short* __restrict__ blp,
    unsigned short* __restrict__ out, int Vout, int T)
{
  constexpr int CHUNKS = CI/32;
  constexpr int NCOL   = NTW*64;
  constexpr int OROW   = NCOL + 8;
  constexpr int ABYTES = 64*CI*2;
  constexpr int SLOTS  = ABYTES/16;
  constexpr int AUS    = SLOTS*8;
  constexpr int NB     = (NSLICE == 1) ? 2 : 1;

  __shared__ __align__(16) unsigned short a_l[NB*AUS];
  __shared__ __align__(16) unsigned short epi[(NSLICE==2) ? 64*OROW : 1];

  const int t = threadIdx.x;
  const int w = t >> 6, l = t & 15, q = (t >> 4) & 3;
  const int lane6 = t & 63;
  const int tix0 = blockIdx.x * T;
  const int coB  = blockIdx.y * NCOL * NSLICE;

  auto stage = [&](int tix, int sel) {
    const size_t m0 = (size_t)tix * 64;
    unsigned short* dst = a_l + (size_t)sel*AUS;
    #pragma unroll
    for (int r = 0; r < SLOTS/256; ++r) {
      const int s    = t + r*256;
      const int c    = s >> 8;
      const int mt   = (s >> 6) & 3;
      const int ql   = s & 63;
      const int m    = mt*16 + (ql & 15);
      const int koff = c*32 + (ql >> 4)*8;
      gload_lds16(A + (m0 + m)*CI + koff, dst + (size_t)s*8);
    }
  };

  if constexpr (NSLICE == 1) {
    stage(tix0, 0);
    __syncthreads();
    for (int j = 0; j < T; ++j) {
      const int tix = tix0 + j;
      const int sel = j & 1;
      if (j + 1 < T) stage(tix + 1, sel ^ 1);

      const unsigned short* ab = a_l + (size_t)sel*AUS;
      f32x4 ah[4][NTW], ax[4][NTW];
      #pragma unroll
      for (int mt = 0; mt < 4; ++mt)
        #pragma unroll
        for (int n = 0; n < NTW; ++n)
          #pragma unroll
          for (int r = 0; r < 4; ++r) { ah[mt][n][r] = 0.f; ax[mt][n][r] = 0.f; }

      #pragma unroll
      for (int c = 0; c < CHUNKS; ++c) {
        const int k0 = c*32 + q*8;
        half8 fa[4], fbh[NTW], fbl[NTW];
        #pragma unroll
        for (int mt = 0; mt < 4; ++mt)
          fa[mt] = *(const half8*)(ab + (size_t)(c*256 + mt*64 + lane6)*8);
        #pragma unroll
        for (int n = 0; n < NTW; ++n) {
          const size_t boff = (size_t)(coB + (w*NTW + n)*16 + l)*CI + k0;
          fbh[n] = *(const half8*)(bhp + boff);
          fbl[n] = *(const half8*)(blp + boff);
        }
        #pragma unroll
        for (int mt = 0; mt < 4; ++mt)
          #pragma unroll
          for (int n = 0; n < NTW; ++n) {
            ah[mt][n] = __builtin_amdgcn_mfma_f32_16x16x32_f16(fa[mt], fbh[n], ah[mt][n], 0, 0, 0);
            ax[mt][n] = __builtin_amdgcn_mfma_f32_16x16x32_f16(fa[mt], fbl[n], ax[mt][n], 0, 0, 0);
          }
      }

      __syncthreads();
      unsigned short (*ot)[OROW] = (unsigned short (*)[OROW])(a_l + (size_t)sel*AUS);
      #pragma unroll
      for (int mt = 0; mt < 4; ++mt)
        #pragma unroll
        for (int n = 0; n < NTW; ++n) {
          const int colg = (w*NTW + n)*16 + l;
          #pragma unroll
          for (int r = 0; r < 4; ++r) {
            const int row = mt*16 + q*4 + r;
            float v = ah[mt][n][r] + ax[mt][n][r] * (1.0f/2048.0f);
            if (RELU) v = fmaxf(v, 0.f);
            ot[row][colg] = hbits(v);
          }
        }
      __syncthreads();
      constexpr int PR = NCOL/8;
      const size_t m0 = (size_t)tix * 64;
      #pragma unroll
      for (int i = 0; i < (64*PR)/256; ++i) {
        const int item = t + i*256;
        const int r  = item / PR;
        const int cp = (item % PR)*8;
        const size_t m = m0 + r;
        const int v = (int)(m >> 4), b = (int)(m & 15);
        *(uint4*)(out + ((size_t)b*Vout + v)*COT + coB + cp) = *(const uint4*)&ot[r][cp];
      }
      __syncthreads();
    }
  } else {
    // NSLICE == 2: single A buffer, two sequential col slices, epi buffer.
    unsigned short (*ot)[OROW] = (unsigned short (*)[OROW])&epi[0];
    for (int j = 0; j < T; ++j) {
      const int tix = tix0 + j;
      stage(tix, 0);
      __syncthreads();
      #pragma unroll 1
      for (int sl = 0; sl < 2; ++sl) {
        const int co0 = coB + sl*NCOL;
        f32x4 ah[4][NTW], ax[4][NTW];
        #pragma unroll
        for (int mt = 0; mt < 4; ++mt)
          #pragma unroll
          for (int n = 0; n < NTW; ++n)
            #pragma unroll
            for (int r = 0; r < 4; ++r) { ah[mt][n][r] = 0.f; ax[mt][n][r] = 0.f; }

        #pragma unroll
        for (int c = 0; c < CHUNKS; ++c) {
          const int k0 = c*32 + q*8;
          half8 fa[4], fbh[NTW], fbl[NTW];
          #pragma unroll
          for (int mt = 0; mt < 4; ++mt)
            fa[mt] = *(const half8*)(a_l + (size_t)(c*256 + mt*64 + lane6)*8);
          #pragma unroll
          for (int n = 0; n < NTW; ++n) {
            const size_t boff = (size_t)(co0 + (w*NTW + n)*16 + l)*CI + k0;
            fbh[n] = *(const half8*)(bhp + boff);
            fbl[n] = *(const half8*)(blp + boff);
          }
          #pragma unroll
          for (int mt = 0; mt < 4; ++mt)
            #pragma unroll
            for (int n = 0; n < NTW; ++n) {
              ah[mt][n] = __builtin_amdgcn_mfma_f32_16x16x32_f16(fa[mt], fbh[n], ah[mt][n], 0, 0, 0);
              ax[mt][n] = __builtin_amdgcn_mfma_f32_16x16x32_f16(fa[mt], fbl[n], ax[mt][n], 0, 0, 0);
            }
        }

        __syncthreads();
        #pragma unroll
        for (int mt = 0; mt < 4; ++mt)
          #pragma unroll
          for (int n = 0; n < NTW; ++n) {
            const int colg = (w*NTW + n)*16 + l;
            #pragma unroll
            for (int r = 0; r < 4; ++r) {
              const int row = mt*16 + q*4 + r;
              float v = ah[mt][n][r] + ax[mt][n][r] * (1.0f/2048.0f);
              if (RELU) v = fmaxf(v, 0.f);
              ot[row][colg] = hbits(v);
            }
          }
        __syncthreads();
        constexpr int PR = NCOL/8;
        const size_t m0 = (size_t)tix * 64;
        #pragma unroll
        for (int i = 0; i < (64*PR)/256; ++i) {
          const int item = t + i*256;
          const int r  = item / PR;
          const int cp = (item % PR)*8;
          const size_t m = m0 + r;
          const int v = (int)(m >> 4), b = (int)(m & 15);
          *(uint4*)(out + ((size_t)b*Vout + v)*COT + co0 + cp) = *(const uint4*)&ot[r][cp];
        }
      }
      __syncthreads();
    }
  }
}

// ---------------- k_gemm_head: lvl4 conv GEMM + fused head -> z ----------------
__global__ __launch_bounds__(256) void k_gemm_head(
    const unsigned short* __restrict__ A,
    const unsigned short* __restrict__ bhp, const unsigned short* __restrict__ blp,
    const unsigned short* __restrict__ bhT, const unsigned short* __restrict__ blT,
    float* __restrict__ z, int T)
{
  constexpr int CI     = 128;
  constexpr int CHUNKS = 4;
  constexpr int OROW   = 80;
  constexpr int ABYTES = 64*CI*2;
  constexpr int SLOTS  = ABYTES/16;
  constexpr int AUS    = SLOTS*8;

  __shared__ __align__(16) unsigned short a_l[2*AUS];
  __shared__ float zt[4][32][16];

  const int t = threadIdx.x;
  const int w = t >> 6, l = t & 15, q = (t >> 4) & 3;
  const int lane6 = t & 63;
  const int tix0 = blockIdx.x * T;

  auto stage = [&](int tix, int sel) {
    const size_t m0 = (size_t)tix * 64;
    unsigned short* dst = a_l + (size_t)sel*AUS;
    #pragma unroll
    for (int r = 0; r < SLOTS/256; ++r) {
      const int s    = t + r*256;
      const int c    = s >> 8;
      const int mt   = (s >> 6) & 3;
      const int ql   = s & 63;
      const int m    = mt*16 + (ql & 15);
      const int koff = c*32 + (ql >> 4)*8;
      gload_lds16(A + (m0 + m)*CI + koff, dst + (size_t)s*8);
    }
  };

  stage(tix0, 0);
  __syncthreads();
  for (int j = 0; j < T; ++j) {
    const int tix = tix0 + j;
    const int sel = j & 1;
    if (j + 1 < T) stage(tix + 1, sel ^ 1);

    const unsigned short* ab = a_l + (size_t)sel*AUS;
    f32x4 ah[4], ax[4];
    #pragma unroll
    for (int mt = 0; mt < 4; ++mt)
      #pragma unroll
      for (int r = 0; r < 4; ++r) { ah[mt][r] = 0.f; ax[mt][r] = 0.f; }

    #pragma unroll
    for (int c = 0; c < CHUNKS; ++c) {
      const int k0 = c*32 + q*8;
      half8 fa[4];
      #pragma unroll
      for (int mt = 0; mt < 4; ++mt)
        fa[mt] = *(const half8*)(ab + (size_t)(c*256 + mt*64 + lane6)*8);
      const size_t boff = (size_t)(w*16 + l)*CI + k0;
      half8 fbh = *(const half8*)(bhp + boff);
      half8 fbl = *(const half8*)(blp + boff);
      #pragma unroll
      for (int mt = 0; mt < 4; ++mt) {
        ah[mt] = __builtin_amdgcn_mfma_f32_16x16x32_f16(fa[mt], fbh, ah[mt], 0, 0, 0);
        ax[mt] = __builtin_amdgcn_mfma_f32_16x16x32_f16(fa[mt], fbl, ax[mt], 0, 0, 0);
      }
    }

    __syncthreads();
    unsigned short (*ot)[OROW] = (unsigned short (*)[OROW])(a_l + (size_t)sel*AUS);
    #pragma unroll
    for (int mt = 0; mt < 4; ++mt) {
      const int colg = w*16 + l;
      #pragma unroll
      for (int r = 0; r < 4; ++r) {
        const int row = mt*16 + q*4 + r;
        float v = ah[mt][r] + ax[mt][r] * (1.0f/2048.0f);
        ot[row][colg] = hbits(fmaxf(v, 0.f));
      }
    }
    __syncthreads();

    {
      f32x4 acch[2], accl[2];
      #pragma unroll
      for (int n = 0; n < 2; ++n)
        #pragma unroll
        for (int r = 0; r < 4; ++r) { acch[n][r] = 0.f; accl[n][r] = 0.f; }
      #pragma unroll
      for (int c = 0; c < 2; ++c) {
        const int k0 = c*32 + q*8;
        half8 fa = *(const half8*)&ot[w*16 + l][k0];
        #pragma unroll
        for (int n = 0; n < 2; ++n) {
          half8 fbh = *(const half8*)(bhT + (size_t)(n*16 + l)*64 + k0);
          half8 fbl = *(const half8*)(blT + (size_t)(n*16 + l)*64 + k0);
          acch[n] = __builtin_amdgcn_mfma_f32_16x16x32_f16(fa, fbh, acch[n], 0, 0, 0);
          accl[n] = __builtin_amdgcn_mfma_f32_16x16x32_f16(fa, fbl, accl[n], 0, 0, 0);
        }
      }
      #pragma unroll
      for (int n = 0; n < 2; ++n)
        #pragma unroll
        for (int r = 0; r < 4; ++r)
          zt[w][n*16 + l][q*4 + r] = acch[n][r] + accl[n][r] * (1.0f/2048.0f);
    }
    __syncthreads();

    const size_t u0 = (size_t)tix * 4;
    #pragma unroll
    for (int i = 0; i < 7; ++i) {
      const int item = t + i*256;
      if (item < 1728) {
        const int ul  = item / 432;
        const int rem = item - ul*432;
        const int s   = rem / 48;
        const int bj  = rem - s*48;
        const int b   = bj / 3;
        const int jj  = bj - b*3;
        z[(u0 + ul)*432 + rem] = zt[ul][s*3 + jj][b];
      }
    }
    __syncthreads();
  }
}

// ---------------- k_head2: gather-sum 9 contiguous 192B slices, out (b, v, 3) ----------------
__global__ __launch_bounds__(256) void k_head2(
    const float* __restrict__ z, const int* __restrict__ idx,
    float* __restrict__ out, int nvert)
{
  const int w    = threadIdx.x >> 6;
  const int lane = threadIdx.x & 63;
  const int v    = blockIdx.x*4 + w;
  if (lane < 48) {
    float acc = 0.f;
    #pragma unroll
    for (int s = 0; s < 9; ++s) {
      const int u = idx[v*9 + s];
      acc += z[(size_t)u*432 + s*48 + lane];
    }
    const int b = lane / 3, j = lane - b*3;
    out[((size_t)b*nvert + v)*3 + j] = acc;
  }
}

extern "C" void kernel_launch(void* const* d_in, const int* in_sizes, int n_in,
                              void* d_out, int out_size, void* d_ws, size_t ws_size,
                              hipStream_t stream)
{
  const float* uv   = (const float*)d_in[0];
  const float* feat = (const float*)d_in[1];
  const float* up   = (const float*)d_in[2];
  const float* dw0  = (const float*)d_in[3];
  const float* pw0  = (const float*)d_in[4];
  const float* dw1  = (const float*)d_in[5];
  const float* pw1  = (const float*)d_in[6];
  const float* dw2  = (const float*)d_in[7];
  const float* pw2  = (const float*)d_in[8];
  const float* dw3  = (const float*)d_in[9];
  const float* pw3  = (const float*)d_in[10];
  const float* dwh  = (const float*)d_in[11];
  const float* pwh  = (const float*)d_in[12];
  const int*   sp0  = (const int*)d_in[13];
  const int*   col0 = (const int*)d_in[14];
  const float* val0 = (const float*)d_in[15];
  const int*   sp1  = (const int*)d_in[16];
  const int*   col1 = (const int*)d_in[17];
  const float* val1 = (const float*)d_in[18];
  const int*   sp2  = (const int*)d_in[19];
  const int*   col2 = (const int*)d_in[20];
  const float* val2 = (const float*)d_in[21];
  const int*   sp3  = (const int*)d_in[22];
  const int*   col3 = (const int*)d_in[23];
  const float* val3 = (const float*)d_in[24];

  unsigned short* bufA  = (unsigned short*)d_ws;
  int*            cidx  = (int*)((char*)d_ws + 25690112);
  float*          cval  = (float*)((char*)d_ws + 28230272);
  unsigned short* bufC  = (unsigned short*)((char*)d_ws + 77070336);
  unsigned short* pwT   = (unsigned short*)((char*)d_ws + 128450560);
  unsigned short* bhead = (unsigned short*)((char*)d_ws + 129138688);
  float*          dwT   = (float*)((char*)d_ws + 129155072);
  float*          zbuf  = (float*)((char*)d_ws + 129187328);
  unsigned short* xs    = (unsigned short*)((char*)d_ws + 150863360);
  float* outp = (float*)d_out;

  unsigned short* h0 = pwT;            unsigned short* L0 = pwT + 172032;
  unsigned short* h1 = pwT + 65536;    unsigned short* L1 = L0 + 65536;
  unsigned short* h2 = pwT + 131072;   unsigned short* L2 = L0 + 131072;
  unsigned short* h3 = pwT + 163840;   unsigned short* L3 = L0 + 163840;
  unsigned short* hh = bhead;          unsigned short* Lh = bhead + 2048;
  float* dwT0 = dwT;          float* dwT1 = dwT + 2304;
  float* dwT2 = dwT + 4608;   float* dwT3 = dwT + 6912;

  k_prep_all<<<712, 256, 0, stream>>>(pw0, pw1, pw2, pw3, dwh, pwh,
                                      dw0, dw1, dw2, dw3, pwT, bhead, dwT);
  k_prep_idx<<<2481, 256, 0, stream>>>(sp3, col3, val3, sp2, col2, val2,
                                       sp1, col1, val1, sp0, col0, val0,
                                       cidx, cval);
  k_samp<<<16, 256, 0, stream>>>(uv, feat, xs);
  k_up<<<dim3(49,16,1), 256, 0, stream>>>(xs, up, bufA);

  // level 1: 784 -> 1568, 256 -> 256  (pdw: VPB=16, VG=98)
  k_pdw<256><<<16*98, 256, 0, stream>>>(bufA, cidx, cval, dwT0, bufC, 784, 98);
  k_gemm<256,256,2,2,true><<<dim3(196,1), 256, 0, stream>>>(bufC, h0, L0, bufA, 1568, 2);

  // level 2: 1568 -> 3136, 256 -> 256  (VG=196)
  k_pdw<256><<<16*196, 256, 0, stream>>>(bufA, cidx + 42336, cval + 42336, dwT1, bufC, 1568, 196);
  k_gemm<256,256,2,2,true><<<dim3(392,1), 256, 0, stream>>>(bufC, h1, L1, bufA, 3136, 2);

  // level 3: 3136 -> 6272, 256 -> 128  (VG=392)
  k_pdw<256><<<16*392, 256, 0, stream>>>(bufA, cidx + 127008, cval + 127008, dwT2, bufC, 3136, 392);
  k_gemm<256,128,2,1,true><<<dim3(392,1), 256, 0, stream>>>(bufC, h2, L2, bufA, 6272, 4);

  // level 4: 6272 -> 12544, 128 -> 64 + FUSED HEAD -> z  (pdw CI=128: VPB=32, VG=392)
  k_pdw<128><<<16*392, 256, 0, stream>>>(bufA, cidx + 296352, cval + 296352, dwT3, bufC, 6272, 392);
  k_gemm_head<<<dim3(784,1), 256, 0, stream>>>(bufC, h3, L3, hh, Lh, zbuf, 4);

  // head finish: contiguous gather-sum
  k_head2<<<3136, 256, 0, stream>>>(zbuf, sp0, outp, 12544);
}

// Round 19
// 400.940 us; speedup vs baseline: 1.1955x; 1.1955x over previous
//
#include <hip/hip_runtime.h>

// ROUND-19 = verbatim revert to round-17 (measured 404.9 us), after round 18's
// pool+dw fusion proved instruction-bound (27-tap gather = 3x issue traffic).
// Activations: BATCH-MAJOR [b][vertex][channel], fp16.
// k_dw: SINGLE-BATCH blocks, XCD-pinned, phase-major -> per-XCD gather slice
// ~3.2MB (~L2). Lean no-LDS panel writer.
// k_gemm: persistent async-LDS A + MFMA.
//   NSLICE=1 (CO=128): double-buffered A, epilogue reuses freed A buffer.
//   NSLICE=2 (CO=256): A staged once/tile, two col slices SEQUENTIAL with
//     "#pragma unroll 1" (round 16: unrolling co-allocated both slices' accs
//     -> VGPR 204 -> occ 7.5%; accs must be reused).
// k_gemm_head (lvl4): conv epilogue tile (relu'd, fp16, in LDS) is exactly
//   headz's A layout -> run K=64 head MFMAs off LDS, write z, skip bufA store.
// d_ws layout:
//   bufA @ 0 (25,690,112) | bufB @ 25,690,112 (51,380,224)
//   bufC @ 77,070,336 (51,380,224) | pwT @ 128,450,560 (688,128)
//   bheadT @ 129,138,688 (16,384) | dwT @ 129,155,072 (32,256)
//   z @ 129,187,328 (21,676,032) | xs @ 150,863,360 (524,288)
// NOTE: never raise __launch_bounds__ min-waves on MFMA kernels (round 5).

typedef _Float16 half8 __attribute__((ext_vector_type(8)));
typedef float    f32x4 __attribute__((ext_vector_type(4)));

__device__ __forceinline__ float4 ld4(const float* p) { return *(const float4*)p; }

__device__ __forceinline__ float lo16f(unsigned u) {
  _Float16 h; unsigned short s = (unsigned short)(u & 0xffffu);
  __builtin_memcpy(&h, &s, 2); return (float)h;
}
__device__ __forceinline__ float hi16f(unsigned u) {
  _Float16 h; unsigned short s = (unsigned short)(u >> 16);
  __builtin_memcpy(&h, &s, 2); return (float)h;
}
__device__ __forceinline__ float h2f(unsigned short s) {
  _Float16 h; __builtin_memcpy(&h, &s, 2); return (float)h;
}
__device__ __forceinline__ unsigned short hbits(float v) {
  _Float16 h = (_Float16)v; unsigned short u; __builtin_memcpy(&u, &h, 2); return u;
}
__device__ __forceinline__ unsigned pk2h(float a, float b) {
  return (unsigned)hbits(a) | ((unsigned)hbits(b) << 16);
}
// split v = hi + lo*2^-11, lo pre-scaled by 2048
__device__ __forceinline__ void split2h(float v, unsigned short& h, unsigned short& l) {
  _Float16 hf = (_Float16)v;
  float hif = (float)hf;
  _Float16 lf = (_Float16)((v - hif) * 2048.0f);
  __builtin_memcpy(&h, &hf, 2); __builtin_memcpy(&l, &lf, 2);
}
// async 16B global -> LDS (no VGPR writeback)
__device__ __forceinline__ void gload_lds16(const unsigned short* g, unsigned short* l) {
  __builtin_amdgcn_global_load_lds(
      (const __attribute__((address_space(1))) unsigned int*)g,
      (__attribute__((address_space(3))) unsigned int*)l, 16, 0, 0);
}

// ---------------- merged prep: pw split tables + head W + dwT transpose ----------------
__global__ __launch_bounds__(256) void k_prep_all(
    const float* __restrict__ pw0, const float* __restrict__ pw1,
    const float* __restrict__ pw2, const float* __restrict__ pw3,
    const float* __restrict__ dwh, const float* __restrict__ pwh,
    const float* __restrict__ dw0, const float* __restrict__ dw1,
    const float* __restrict__ dw2, const float* __restrict__ dw3,
    unsigned short* __restrict__ dstPw, unsigned short* __restrict__ dstHead,
    float* __restrict__ dstDw)
{
  const int blk = blockIdx.x, t = threadIdx.x;
  if (blk < 672) {
    const int b = blk;
    const float* src; int ci_sh, co, f, off;
    if (b < 256)      { src = pw0; ci_sh = 8; co = 256; f = b*256 + t;       off = 0; }
    else if (b < 512) { src = pw1; ci_sh = 8; co = 256; f = (b-256)*256 + t; off = 65536; }
    else if (b < 640) { src = pw2; ci_sh = 8; co = 128; f = (b-512)*256 + t; off = 131072; }
    else              { src = pw3; ci_sh = 7; co = 64;  f = (b-640)*256 + t; off = 163840; }
    const int n = f >> ci_sh, k = f & ((1 << ci_sh) - 1);
    float v = src[(size_t)k*co + n];
    unsigned short h, l; split2h(v, h, l);
    dstPw[off + f]          = h;
    dstPw[172032 + off + f] = l;
  } else if (blk < 680) {
    const int i = (blk - 672)*256 + t;   // 2048 = 32*64
    const int n = i >> 6, c = i & 63;
    float v = 0.f;
    if (n < 27) v = dwh[c*9 + n/3] * pwh[c*3 + n%3];
    unsigned short h, l; split2h(v, h, l);
    dstHead[i] = h; dstHead[2048 + i] = l;
  } else {
    const int i = (blk - 680)*256 + t;
    if (i >= 8064) return;
    const float* src; int rel, C, off;
    if (i < 2304)      { src = dw0; rel = i;        C = 256; off = 0; }
    else if (i < 4608) { src = dw1; rel = i - 2304; C = 256; off = 2304; }
    else if (i < 6912) { src = dw2; rel = i - 4608; C = 256; off = 4608; }
    else               { src = dw3; rel = i - 6912; C = 128; off = 6912; }
    const int s = rel / C, c = rel % C;
    dstDw[off + rel] = src[c*9 + s];
  }
}

// ---------------- k_samp: grid-sample only -> xs[b][p][c] fp16 (16 blocks) ----------------
__global__ __launch_bounds__(256) void k_samp(
    const float* __restrict__ uv, const float* __restrict__ feat,
    unsigned short* __restrict__ xs)
{
  __shared__ float feat_l[256][17];
  const int tid = threadIdx.x;
  const int b   = blockIdx.x;

  const float* fr = feat + ((size_t)b*256 + tid)*16;
  #pragma unroll
  for (int i = 0; i < 16; i += 4) {
    float4 f = ld4(fr + i);
    feat_l[tid][i+0] = f.x; feat_l[tid][i+1] = f.y;
    feat_l[tid][i+2] = f.z; feat_l[tid][i+3] = f.w;
  }
  #pragma unroll 4
  for (int p = 0; p < 64; ++p) {
    float gx = uv[((size_t)b*64 + p)*2 + 0];
    float gy = uv[((size_t)b*64 + p)*2 + 1];
    gx = fminf(fmaxf((gx - 0.5f)*2.f, -1.f), 1.f);
    gy = fminf(fmaxf((gy - 0.5f)*2.f, -1.f), 1.f);
    float x = (gx + 1.f)*0.5f*3.f;
    float y = (gy + 1.f)*0.5f*3.f;
    float fx = floorf(x), fy = floorf(y);
    int ix0 = (int)fx, iy0 = (int)fy;
    float wx = x - fx, wy = y - fy;
    int ix1 = ix0 + 1 > 3 ? 3 : ix0 + 1;
    int iy1 = iy0 + 1 > 3 ? 3 : iy0 + 1;
    float v00 = feat_l[tid][iy0*4+ix0];
    float v01 = feat_l[tid][iy0*4+ix1];
    float v10 = feat_l[tid][iy1*4+ix0];
    float v11 = feat_l[tid][iy1*4+ix1];
    float xv = (1.f-wy)*((1.f-wx)*v00 + wx*v01) + wy*((1.f-wx)*v10 + wx*v11);
    xs[((size_t)b*64 + p)*256 + tid] = hbits(xv);
  }
}

// ---------------- k_up: x0[b][v][c] = sum_p up[v][p]*xs[b][p][c], 16 verts/block ----------------
__global__ __launch_bounds__(256) void k_up(
    const unsigned short* __restrict__ xs, const float* __restrict__ up,
    unsigned short* __restrict__ x0)
{
  const int tid = threadIdx.x;
  const int b   = blockIdx.y;
  const int v0  = blockIdx.x * 16;

  float acc[16];
  #pragma unroll
  for (int i = 0; i < 16; ++i) acc[i] = 0.f;

  #pragma unroll 8
  for (int p = 0; p < 64; ++p) {
    const float xv = h2f(xs[((size_t)b*64 + p)*256 + tid]);
    #pragma unroll
    for (int i = 0; i < 16; ++i)
      acc[i] += up[(size_t)(v0+i)*64 + p] * xv;   // wave-uniform -> scalar
  }
  #pragma unroll
  for (int i = 0; i < 16; ++i)
    x0[((size_t)b*784 + v0 + i)*256 + tid] = hbits(acc[i]);
}

// ---------------- mesh up-pool: [b][Vin][C] -> [b][Vout][C], XCD-pinned batch pair ----------------
template<int C>
__global__ __launch_bounds__(256) void k_pool(
    const unsigned short* __restrict__ x, const int* __restrict__ col,
    const float* __restrict__ val, unsigned short* __restrict__ out,
    int Vin, int Vout)
{
  constexpr int KGc = C/8;        // uint4 units per row
  constexpr int UPB = 2*KGc;      // units per vertex (2 batches)
  const int bp = blockIdx.x & 7;
  const int v0 = (blockIdx.x >> 3) * 8;
  const int t  = threadIdx.x;

  #pragma unroll
  for (int i = 0; i < (8*UPB)/256; ++i) {
    const int id = t + i*256;
    const int vl = id / UPB;
    const int rem = id - vl*UPB;
    const int bl = rem / KGc;
    const int kg = rem - bl*KGc;
    const int v  = v0 + vl;
    const int b  = 2*bp + bl;
    const int c0 = col[3*v+0], c1 = col[3*v+1], c2 = col[3*v+2];
    const float w0 = val[3*v+0], w1 = val[3*v+1], w2 = val[3*v+2];
    const uint4 A = *(const uint4*)(x + ((size_t)b*Vin + c0)*C + 8*kg);
    const uint4 B = *(const uint4*)(x + ((size_t)b*Vin + c1)*C + 8*kg);
    const uint4 Cv= *(const uint4*)(x + ((size_t)b*Vin + c2)*C + 8*kg);
    uint4 R;
    R.x = pk2h(w0*lo16f(A.x)+w1*lo16f(B.x)+w2*lo16f(Cv.x),
               w0*hi16f(A.x)+w1*hi16f(B.x)+w2*hi16f(Cv.x));
    R.y = pk2h(w0*lo16f(A.y)+w1*lo16f(B.y)+w2*lo16f(Cv.y),
               w0*hi16f(A.y)+w1*hi16f(B.y)+w2*hi16f(Cv.y));
    R.z = pk2h(w0*lo16f(A.z)+w1*lo16f(B.z)+w2*lo16f(Cv.z),
               w0*hi16f(A.z)+w1*hi16f(B.z)+w2*hi16f(Cv.z));
    R.w = pk2h(w0*lo16f(A.w)+w1*lo16f(B.w)+w2*lo16f(Cv.w),
               w0*hi16f(A.w)+w1*hi16f(B.w)+w2*hi16f(Cv.w));
    *(uint4*)(out + ((size_t)b*Vout + v)*C + 8*kg) = R;
  }
}

// ---------------- k_dw: spiral-gather + depthwise conv -> m-major panel ----------------
// SINGLE-BATCH blocks: XCD = blockIdx%8, phase-major (i<VG: b=XCD; else b=XCD+8).
template<int CI>
__global__ __launch_bounds__(256) void k_dw(
    const unsigned short* __restrict__ pin, const int* __restrict__ idx,
    const float* __restrict__ dwT, unsigned short* __restrict__ aout,
    int Vin, int VG)
{
  constexpr int KG    = CI/8;
  constexpr int SLOTS = 256/KG;     // row slots per block
  constexpr int VPB   = 2*SLOTS;    // vertices per block (2 per thread)

  const int t     = threadIdx.x;
  const int xcd   = blockIdx.x & 7;
  const int i     = blockIdx.x >> 3;
  const int phase = (i >= VG) ? 1 : 0;
  const int vg    = i - phase*VG;
  const int b     = xcd + 8*phase;
  const int kg    = t & (KG - 1);
  const int slot  = t / KG;
  const int va    = vg*VPB + slot;
  const int vb2   = va + SLOTS;

  const unsigned short* base = pin + (size_t)b*Vin*CI + 8*kg;
  float y0[8], y1[8];
  #pragma unroll
  for (int j = 0; j < 8; ++j) { y0[j] = 0.f; y1[j] = 0.f; }

  #pragma unroll
  for (int s = 0; s < 9; ++s) {
    const float4 wa = *(const float4*)(dwT + s*CI + 8*kg);
    const float4 wb = *(const float4*)(dwT + s*CI + 8*kg + 4);
    const uint4 g0 = *(const uint4*)(base + (size_t)idx[va *9 + s]*CI);
    const uint4 g1 = *(const uint4*)(base + (size_t)idx[vb2*9 + s]*CI);
    y0[0] += wa.x*lo16f(g0.x); y0[1] += wa.y*hi16f(g0.x);
    y0[2] += wa.z*lo16f(g0.y); y0[3] += wa.w*hi16f(g0.y);
    y0[4] += wb.x*lo16f(g0.z); y0[5] += wb.y*hi16f(g0.z);
    y0[6] += wb.z*lo16f(g0.w); y0[7] += wb.w*hi16f(g0.w);
    y1[0] += wa.x*lo16f(g1.x); y1[1] += wa.y*hi16f(g1.x);
    y1[2] += wa.z*lo16f(g1.y); y1[3] += wa.w*hi16f(g1.y);
    y1[4] += wb.x*lo16f(g1.z); y1[5] += wb.y*hi16f(g1.z);
    y1[6] += wb.z*lo16f(g1.w); y1[7] += wb.w*hi16f(g1.w);
  }
  uint4 p0, p1;
  p0.x = pk2h(y0[0], y0[1]); p0.y = pk2h(y0[2], y0[3]);
  p0.z = pk2h(y0[4], y0[5]); p0.w = pk2h(y0[6], y0[7]);
  p1.x = pk2h(y1[0], y1[1]); p1.y = pk2h(y1[2], y1[3]);
  p1.z = pk2h(y1[4], y1[5]); p1.w = pk2h(y1[6], y1[7]);
  *(uint4*)(aout + (size_t)(va *16 + b)*CI + 8*kg) = p0;
  *(uint4*)(aout + (size_t)(vb2*16 + b)*CI + 8*kg) = p1;
}

// ---------------- k_gemm: persistent async-LDS A + MFMA ----------------
// NSLICE=1: double-buffered A, epilogue reuses freed A buffer.
// NSLICE=2: single A buffer, two SEQUENTIAL col slices (unroll 1 -> accs
// reused), separate epi buffer.  D = Ah*Bh + Ah*Bl*2^-11.  Out [b][V][COT].
template<int CI, int COT, int NTW, int NSLICE, bool RELU>
__global__ __launch_bounds__(256) void k_gemm(
    const unsigned short* __restrict__ A,
    const unsigned short* __restrict__ bhp, const unsigned short* __restrict__ blp,
    unsigned short* __restrict__ out, int Vout, int T)
{
  constexpr int CHUNKS = CI/32;
  constexpr int NCOL   = NTW*64;
  constexpr int OROW   = NCOL + 8;
  constexpr int ABYTES = 64*CI*2;
  constexpr int SLOTS  = ABYTES/16;     // 16B slots per tile
  constexpr int AUS    = SLOTS*8;       // ushorts per buffer
  constexpr int NB     = (NSLICE == 1) ? 2 : 1;

  __shared__ __align__(16) unsigned short a_l[NB*AUS];
  __shared__ __align__(16) unsigned short epi[(NSLICE==2) ? 64*OROW : 1];

  const int t = threadIdx.x;
  const int w = t >> 6, l = t & 15, q = (t >> 4) & 3;
  const int lane6 = t & 63;
  const int tix0 = blockIdx.x * T;
  const int coB  = blockIdx.y * NCOL * NSLICE;

  auto stage = [&](int tix, int sel) {
    const size_t m0 = (size_t)tix * 64;
    unsigned short* dst = a_l + (size_t)sel*AUS;
    #pragma unroll
    for (int r = 0; r < SLOTS/256; ++r) {
      const int s    = t + r*256;
      const int c    = s >> 8;
      const int mt   = (s >> 6) & 3;
      const int ql   = s & 63;
      const int m    = mt*16 + (ql & 15);
      const int koff = c*32 + (ql >> 4)*8;
      gload_lds16(A + (m0 + m)*CI + koff, dst + (size_t)s*8);
    }
  };

  if constexpr (NSLICE == 1) {
    stage(tix0, 0);
    __syncthreads();
    for (int j = 0; j < T; ++j) {
      const int tix = tix0 + j;
      const int sel = j & 1;
      if (j + 1 < T) stage(tix + 1, sel ^ 1);

      const unsigned short* ab = a_l + (size_t)sel*AUS;
      f32x4 ah[4][NTW], ax[4][NTW];
      #pragma unroll
      for (int mt = 0; mt < 4; ++mt)
        #pragma unroll
        for (int n = 0; n < NTW; ++n)
          #pragma unroll
          for (int r = 0; r < 4; ++r) { ah[mt][n][r] = 0.f; ax[mt][n][r] = 0.f; }

      #pragma unroll
      for (int c = 0; c < CHUNKS; ++c) {
        const int k0 = c*32 + q*8;
        half8 fa[4], fbh[NTW], fbl[NTW];
        #pragma unroll
        for (int mt = 0; mt < 4; ++mt)
          fa[mt] = *(const half8*)(ab + (size_t)(c*256 + mt*64 + lane6)*8);
        #pragma unroll
        for (int n = 0; n < NTW; ++n) {
          const size_t boff = (size_t)(coB + (w*NTW + n)*16 + l)*CI + k0;
          fbh[n] = *(const half8*)(bhp + boff);
          fbl[n] = *(const half8*)(blp + boff);
        }
        #pragma unroll
        for (int mt = 0; mt < 4; ++mt)
          #pragma unroll
          for (int n = 0; n < NTW; ++n) {
            ah[mt][n] = __builtin_amdgcn_mfma_f32_16x16x32_f16(fa[mt], fbh[n], ah[mt][n], 0, 0, 0);
            ax[mt][n] = __builtin_amdgcn_mfma_f32_16x16x32_f16(fa[mt], fbl[n], ax[mt][n], 0, 0, 0);
          }
      }

      __syncthreads();
      unsigned short (*ot)[OROW] = (unsigned short (*)[OROW])(a_l + (size_t)sel*AUS);
      #pragma unroll
      for (int mt = 0; mt < 4; ++mt)
        #pragma unroll
        for (int n = 0; n < NTW; ++n) {
          const int colg = (w*NTW + n)*16 + l;
          #pragma unroll
          for (int r = 0; r < 4; ++r) {
            const int row = mt*16 + q*4 + r;
            float v = ah[mt][n][r] + ax[mt][n][r] * (1.0f/2048.0f);
            if (RELU) v = fmaxf(v, 0.f);
            ot[row][colg] = hbits(v);
          }
        }
      __syncthreads();
      constexpr int PR = NCOL/8;
      const size_t m0 = (size_t)tix * 64;
      #pragma unroll
      for (int i = 0; i < (64*PR)/256; ++i) {
        const int item = t + i*256;
        const int r  = item / PR;
        const int cp = (item % PR)*8;
        const size_t m = m0 + r;
        const int v = (int)(m >> 4), b = (int)(m & 15);
        *(uint4*)(out + ((size_t)b*Vout + v)*COT + coB + cp) = *(const uint4*)&ot[r][cp];
      }
      __syncthreads();
    }
  } else {
    // NSLICE == 2: single A buffer, two sequential col slices, epi buffer.
    // "unroll 1" is load-bearing: unrolling co-allocates both slices' accs.
    unsigned short (*ot)[OROW] = (unsigned short (*)[OROW])&epi[0];
    for (int j = 0; j < T; ++j) {
      const int tix = tix0 + j;
      stage(tix, 0);
      __syncthreads();                 // A ready (drains vmcnt per barrier)
      #pragma unroll 1
      for (int sl = 0; sl < 2; ++sl) {
        const int co0 = coB + sl*NCOL;
        f32x4 ah[4][NTW], ax[4][NTW];
        #pragma unroll
        for (int mt = 0; mt < 4; ++mt)
          #pragma unroll
          for (int n = 0; n < NTW; ++n)
            #pragma unroll
            for (int r = 0; r < 4; ++r) { ah[mt][n][r] = 0.f; ax[mt][n][r] = 0.f; }

        #pragma unroll
        for (int c = 0; c < CHUNKS; ++c) {
          const int k0 = c*32 + q*8;
          half8 fa[4], fbh[NTW], fbl[NTW];
          #pragma unroll
          for (int mt = 0; mt < 4; ++mt)
            fa[mt] = *(const half8*)(a_l + (size_t)(c*256 + mt*64 + lane6)*8);
          #pragma unroll
          for (int n = 0; n < NTW; ++n) {
            const size_t boff = (size_t)(co0 + (w*NTW + n)*16 + l)*CI + k0;
            fbh[n] = *(const half8*)(bhp + boff);
            fbl[n] = *(const half8*)(blp + boff);
          }
          #pragma unroll
          for (int mt = 0; mt < 4; ++mt)
            #pragma unroll
            for (int n = 0; n < NTW; ++n) {
              ah[mt][n] = __builtin_amdgcn_mfma_f32_16x16x32_f16(fa[mt], fbh[n], ah[mt][n], 0, 0, 0);
              ax[mt][n] = __builtin_amdgcn_mfma_f32_16x16x32_f16(fa[mt], fbl[n], ax[mt][n], 0, 0, 0);
            }
        }

        __syncthreads();               // prior epi store-reads done
        #pragma unroll
        for (int mt = 0; mt < 4; ++mt)
          #pragma unroll
          for (int n = 0; n < NTW; ++n) {
            const int colg = (w*NTW + n)*16 + l;
            #pragma unroll
            for (int r = 0; r < 4; ++r) {
              const int row = mt*16 + q*4 + r;
              float v = ah[mt][n][r] + ax[mt][n][r] * (1.0f/2048.0f);
              if (RELU) v = fmaxf(v, 0.f);
              ot[row][colg] = hbits(v);
            }
          }
        __syncthreads();
        constexpr int PR = NCOL/8;
        const size_t m0 = (size_t)tix * 64;
        #pragma unroll
        for (int i = 0; i < (64*PR)/256; ++i) {
          const int item = t + i*256;
          const int r  = item / PR;
          const int cp = (item % PR)*8;
          const size_t m = m0 + r;
          const int v = (int)(m >> 4), b = (int)(m & 15);
          *(uint4*)(out + ((size_t)b*Vout + v)*COT + co0 + cp) = *(const uint4*)&ot[r][cp];
        }
      }
      __syncthreads();                 // all A ds-reads + epi reads drained before restage
    }
  }
}

// ---------------- k_gemm_head: lvl4 conv GEMM + fused head -> z ----------------
// CI=128, CO=64, double-buffered A. Conv tile (relu'd fp16) staged in LDS is
// exactly headz's A layout (wave w = vertex u0+w x 16 batches); head MFMAs
// (K=64, N=32 hi/lo) run off LDS; z written directly; NO bufA store.
__global__ __launch_bounds__(256) void k_gemm_head(
    const unsigned short* __restrict__ A,
    const unsigned short* __restrict__ bhp, const unsigned short* __restrict__ blp,
    const unsigned short* __restrict__ bhT, const unsigned short* __restrict__ blT,
    float* __restrict__ z, int T)
{
  constexpr int CI     = 128;
  constexpr int CHUNKS = 4;
  constexpr int OROW   = 80;            // 160B row stride -> 16B-aligned half8 reads
  constexpr int ABYTES = 64*CI*2;       // 16KB
  constexpr int SLOTS  = ABYTES/16;     // 1024
  constexpr int AUS    = SLOTS*8;

  __shared__ __align__(16) unsigned short a_l[2*AUS];  // 32KB
  __shared__ float zt[4][32][16];                      // 8KB

  const int t = threadIdx.x;
  const int w = t >> 6, l = t & 15, q = (t >> 4) & 3;
  const int lane6 = t & 63;
  const int tix0 = blockIdx.x * T;

  auto stage = [&](int tix, int sel) {
    const size_t m0 = (size_t)tix * 64;
    unsigned short* dst = a_l + (size_t)sel*AUS;
    #pragma unroll
    for (int r = 0; r < SLOTS/256; ++r) {
      const int s    = t + r*256;
      const int c    = s >> 8;
      const int mt   = (s >> 6) & 3;
      const int ql   = s & 63;
      const int m    = mt*16 + (ql & 15);
      const int koff = c*32 + (ql >> 4)*8;
      gload_lds16(A + (m0 + m)*CI + koff, dst + (size_t)s*8);
    }
  };

  stage(tix0, 0);
  __syncthreads();
  for (int j = 0; j < T; ++j) {
    const int tix = tix0 + j;
    const int sel = j & 1;
    if (j + 1 < T) stage(tix + 1, sel ^ 1);

    // ---- conv MFMA (NTW=1) ----
    const unsigned short* ab = a_l + (size_t)sel*AUS;
    f32x4 ah[4], ax[4];
    #pragma unroll
    for (int mt = 0; mt < 4; ++mt)
      #pragma unroll
      for (int r = 0; r < 4; ++r) { ah[mt][r] = 0.f; ax[mt][r] = 0.f; }

    #pragma unroll
    for (int c = 0; c < CHUNKS; ++c) {
      const int k0 = c*32 + q*8;
      half8 fa[4];
      #pragma unroll
      for (int mt = 0; mt < 4; ++mt)
        fa[mt] = *(const half8*)(ab + (size_t)(c*256 + mt*64 + lane6)*8);
      const size_t boff = (size_t)(w*16 + l)*CI + k0;
      half8 fbh = *(const half8*)(bhp + boff);
      half8 fbl = *(const half8*)(blp + boff);
      #pragma unroll
      for (int mt = 0; mt < 4; ++mt) {
        ah[mt] = __builtin_amdgcn_mfma_f32_16x16x32_f16(fa[mt], fbh, ah[mt], 0, 0, 0);
        ax[mt] = __builtin_amdgcn_mfma_f32_16x16x32_f16(fa[mt], fbl, ax[mt], 0, 0, 0);
      }
    }

    __syncthreads();   // ab reads done; stage(j+1) drained
    unsigned short (*ot)[OROW] = (unsigned short (*)[OROW])(a_l + (size_t)sel*AUS);
    #pragma unroll
    for (int mt = 0; mt < 4; ++mt) {
      const int colg = w*16 + l;
      #pragma unroll
      for (int r = 0; r < 4; ++r) {
        const int row = mt*16 + q*4 + r;
        float v = ah[mt][r] + ax[mt][r] * (1.0f/2048.0f);
        ot[row][colg] = hbits(fmaxf(v, 0.f));
      }
    }
    __syncthreads();   // ot complete

    // ---- fused head: zrow = ot(w*16+l) @ Whead (K=64, N=32 hi/lo) ----
    {
      f32x4 acch[2], accl[2];
      #pragma unroll
      for (int n = 0; n < 2; ++n)
        #pragma unroll
        for (int r = 0; r < 4; ++r) { acch[n][r] = 0.f; accl[n][r] = 0.f; }
      #pragma unroll
      for (int c = 0; c < 2; ++c) {
        const int k0 = c*32 + q*8;
        half8 fa = *(const half8*)&ot[w*16 + l][k0];
        #pragma unroll
        for (int n = 0; n < 2; ++n) {
          half8 fbh = *(const half8*)(bhT + (size_t)(n*16 + l)*64 + k0);
          half8 fbl = *(const half8*)(blT + (size_t)(n*16 + l)*64 + k0);
          acch[n] = __builtin_amdgcn_mfma_f32_16x16x32_f16(fa, fbh, acch[n], 0, 0, 0);
          accl[n] = __builtin_amdgcn_mfma_f32_16x16x32_f16(fa, fbl, accl[n], 0, 0, 0);
        }
      }
      #pragma unroll
      for (int n = 0; n < 2; ++n)
        #pragma unroll
        for (int r = 0; r < 4; ++r)
          zt[w][n*16 + l][q*4 + r] = acch[n][r] + accl[n][r] * (1.0f/2048.0f);
    }
    __syncthreads();   // zt complete

    // z[u][s*48 + b*3 + j], u0 = tix*4, 1728 floats per tile
    const size_t u0 = (size_t)tix * 4;
    #pragma unroll
    for (int i = 0; i < 7; ++i) {
      const int item = t + i*256;
      if (item < 1728) {
        const int ul  = item / 432;
        const int rem = item - ul*432;
        const int s   = rem / 48;
        const int bj  = rem - s*48;
        const int b   = bj / 3;
        const int jj  = bj - b*3;
        z[(u0 + ul)*432 + rem] = zt[ul][s*3 + jj][b];
      }
    }
    __syncthreads();   // zt/ot reads done before restage of buf[sel]
  }
}

// ---------------- k_head2: gather-sum 9 contiguous 192B slices, out (b, v, 3) ----------------
__global__ __launch_bounds__(256) void k_head2(
    const float* __restrict__ z, const int* __restrict__ idx,
    float* __restrict__ out, int nvert)
{
  const int w    = threadIdx.x >> 6;
  const int lane = threadIdx.x & 63;
  const int v    = blockIdx.x*4 + w;
  if (lane < 48) {
    float acc = 0.f;
    #pragma unroll
    for (int s = 0; s < 9; ++s) {
      const int u = idx[v*9 + s];
      acc += z[(size_t)u*432 + s*48 + lane];
    }
    const int b = lane / 3, j = lane - b*3;
    out[((size_t)b*nvert + v)*3 + j] = acc;
  }
}

extern "C" void kernel_launch(void* const* d_in, const int* in_sizes, int n_in,
                              void* d_out, int out_size, void* d_ws, size_t ws_size,
                              hipStream_t stream)
{
  const float* uv   = (const float*)d_in[0];
  const float* feat = (const float*)d_in[1];
  const float* up   = (const float*)d_in[2];
  const float* dw0  = (const float*)d_in[3];
  const float* pw0  = (const float*)d_in[4];
  const float* dw1  = (const float*)d_in[5];
  const float* pw1  = (const float*)d_in[6];
  const float* dw2  = (const float*)d_in[7];
  const float* pw2  = (const float*)d_in[8];
  const float* dw3  = (const float*)d_in[9];
  const float* pw3  = (const float*)d_in[10];
  const float* dwh  = (const float*)d_in[11];
  const float* pwh  = (const float*)d_in[12];
  const int*   sp0  = (const int*)d_in[13];
  const int*   col0 = (const int*)d_in[14];
  const float* val0 = (const float*)d_in[15];
  const int*   sp1  = (const int*)d_in[16];
  const int*   col1 = (const int*)d_in[17];
  const float* val1 = (const float*)d_in[18];
  const int*   sp2  = (const int*)d_in[19];
  const int*   col2 = (const int*)d_in[20];
  const float* val2 = (const float*)d_in[21];
  const int*   sp3  = (const int*)d_in[22];
  const int*   col3 = (const int*)d_in[23];
  const float* val3 = (const float*)d_in[24];

  unsigned short* bufA  = (unsigned short*)d_ws;
  unsigned short* bufB  = (unsigned short*)((char*)d_ws + 25690112);
  unsigned short* bufC  = (unsigned short*)((char*)d_ws + 77070336);
  unsigned short* pwT   = (unsigned short*)((char*)d_ws + 128450560);
  unsigned short* bhead = (unsigned short*)((char*)d_ws + 129138688);
  float*          dwT   = (float*)((char*)d_ws + 129155072);
  float*          zbuf  = (float*)((char*)d_ws + 129187328);
  unsigned short* xs    = (unsigned short*)((char*)d_ws + 150863360);
  float* outp = (float*)d_out;

  unsigned short* h0 = pwT;            unsigned short* L0 = pwT + 172032;
  unsigned short* h1 = pwT + 65536;    unsigned short* L1 = L0 + 65536;
  unsigned short* h2 = pwT + 131072;   unsigned short* L2 = L0 + 131072;
  unsigned short* h3 = pwT + 163840;   unsigned short* L3 = L0 + 163840;
  unsigned short* hh = bhead;          unsigned short* Lh = bhead + 2048;
  float* dwT0 = dwT;          float* dwT1 = dwT + 2304;
  float* dwT2 = dwT + 4608;   float* dwT3 = dwT + 6912;

  k_prep_all<<<712, 256, 0, stream>>>(pw0, pw1, pw2, pw3, dwh, pwh,
                                      dw0, dw1, dw2, dw3, pwT, bhead, dwT);
  k_samp<<<16, 256, 0, stream>>>(uv, feat, xs);
  k_up<<<dim3(49,16,1), 256, 0, stream>>>(xs, up, bufA);

  // level 1: 784 -> 1568, 256 -> 256  (392 M-tiles; T=2, NSLICE=2 -> 196 blocks)
  k_pool<256><<<1568, 256, 0, stream>>>(bufA, col3, val3, bufB, 784, 1568);
  k_dw<256><<<16*98, 256, 0, stream>>>(bufB, sp3, dwT0, bufC, 1568, 98);
  k_gemm<256,256,2,2,true><<<dim3(196,1), 256, 0, stream>>>(bufC, h0, L0, bufA, 1568, 2);

  // level 2: 1568 -> 3136, 256 -> 256  (784 M-tiles; T=2, NSLICE=2 -> 392 blocks)
  k_pool<256><<<3136, 256, 0, stream>>>(bufA, col2, val2, bufB, 1568, 3136);
  k_dw<256><<<16*196, 256, 0, stream>>>(bufB, sp2, dwT1, bufC, 3136, 196);
  k_gemm<256,256,2,2,true><<<dim3(392,1), 256, 0, stream>>>(bufC, h1, L1, bufA, 3136, 2);

  // level 3: 3136 -> 6272, 256 -> 128  (1568 M-tiles; T=4 -> 392 blocks)
  k_pool<256><<<6272, 256, 0, stream>>>(bufA, col1, val1, bufB, 3136, 6272);
  k_dw<256><<<16*392, 256, 0, stream>>>(bufB, sp1, dwT2, bufC, 6272, 392);
  k_gemm<256,128,2,1,true><<<dim3(392,1), 256, 0, stream>>>(bufC, h2, L2, bufA, 6272, 4);

  // level 4: 6272 -> 12544, 128 -> 64 + FUSED HEAD -> z  (3136 M-tiles; T=4)
  k_pool<128><<<12544, 256, 0, stream>>>(bufA, col0, val0, bufB, 6272, 12544);
  k_dw<128><<<16*392, 256, 0, stream>>>(bufB, sp0, dwT3, bufC, 12544, 392);
  k_gemm_head<<<dim3(784,1), 256, 0, stream>>>(bufC, h3, L3, hh, Lh, zbuf, 4);

  // head finish: contiguous gather-sum
  k_head2<<<3136, 256, 0, stream>>>(zbuf, sp0, outp, 12544);
}